// Round 1
// baseline (4159.034 us; speedup 1.0000x reference)
//
#include <hip/hip_runtime.h>
#include <cstdint>
#include <cstddef>

#define T_N 4096
#define I_N 2048
#define H_N 2048
#define K_N 3

// ---------------------------------------------------------------
// K1: fused gates GEMM: gi = x @ W_ih^T (+biases) -> activations -> H_all
// Tile: 64 t-rows x 64 j-cols, fixed k, all 3 gates per block.
// ---------------------------------------------------------------
constexpr int TM = 64, TN = 64, KB = 32;

__global__ __launch_bounds__(256) void k_gates(
    const float* __restrict__ x, const float* __restrict__ Wih,
    const float* __restrict__ bih, const float* __restrict__ bhh,
    float* __restrict__ Hall)
{
  __shared__ float As[KB][TM];      // [i][t] transposed
  __shared__ float Bs[3][KB][TN];   // [gate][i][j] transposed
  const int bt = blockIdx.x * TM;
  const int bj = blockIdx.y * TN;
  const int k  = blockIdx.z;
  const int tid = threadIdx.x;
  const int tx = tid & 15, ty = tid >> 4;
  const int lr = tid >> 3;          // load row 0..31
  const int lc = (tid & 7) * 4;     // load col 0..28 step 4

  float acc[3][4][4];
  #pragma unroll
  for (int g = 0; g < 3; ++g)
    #pragma unroll
    for (int r = 0; r < 4; ++r)
      #pragma unroll
      for (int c = 0; c < 4; ++c) acc[g][r][c] = 0.f;

  const size_t wbase = (size_t)k * 3 * H_N;   // row base into (K,3H) tensors

  for (int kb = 0; kb < I_N; kb += KB) {
    #pragma unroll
    for (int h = 0; h < 2; ++h) {
      const int row = lr + h * 32;
      const float4 v = *reinterpret_cast<const float4*>(
          &x[(size_t)(bt + row) * I_N + kb + lc]);
      As[lc + 0][row] = v.x; As[lc + 1][row] = v.y;
      As[lc + 2][row] = v.z; As[lc + 3][row] = v.w;
    }
    #pragma unroll
    for (int g = 0; g < 3; ++g) {
      #pragma unroll
      for (int h = 0; h < 2; ++h) {
        const int row = lr + h * 32;   // j within tile
        const float4 v = *reinterpret_cast<const float4*>(
            &Wih[(wbase + (size_t)g * H_N + bj + row) * I_N + kb + lc]);
        Bs[g][lc + 0][row] = v.x; Bs[g][lc + 1][row] = v.y;
        Bs[g][lc + 2][row] = v.z; Bs[g][lc + 3][row] = v.w;
      }
    }
    __syncthreads();
    #pragma unroll
    for (int c = 0; c < KB; ++c) {
      const float4 a  = *reinterpret_cast<const float4*>(&As[c][ty * 4]);
      const float4 b0 = *reinterpret_cast<const float4*>(&Bs[0][c][tx * 4]);
      const float4 b1 = *reinterpret_cast<const float4*>(&Bs[1][c][tx * 4]);
      const float4 b2 = *reinterpret_cast<const float4*>(&Bs[2][c][tx * 4]);
      const float av[4]  = {a.x, a.y, a.z, a.w};
      const float b0v[4] = {b0.x, b0.y, b0.z, b0.w};
      const float b1v[4] = {b1.x, b1.y, b1.z, b1.w};
      const float b2v[4] = {b2.x, b2.y, b2.z, b2.w};
      #pragma unroll
      for (int r = 0; r < 4; ++r)
        #pragma unroll
        for (int c2 = 0; c2 < 4; ++c2) {
          acc[0][r][c2] = fmaf(av[r], b0v[c2], acc[0][r][c2]);
          acc[1][r][c2] = fmaf(av[r], b1v[c2], acc[1][r][c2]);
          acc[2][r][c2] = fmaf(av[r], b2v[c2], acc[2][r][c2]);
        }
    }
    __syncthreads();
  }

  #pragma unroll
  for (int r = 0; r < 4; ++r) {
    const int t = bt + ty * 4 + r;
    float ov[4];
    #pragma unroll
    for (int c2 = 0; c2 < 4; ++c2) {
      const int j = bj + tx * 4 + c2;
      const float irv = acc[0][r][c2] + bih[wbase + j]           + bhh[wbase + j];
      const float izv = acc[1][r][c2] + bih[wbase + H_N + j]     + bhh[wbase + H_N + j];
      const float hn  = bhh[wbase + 2 * H_N + j];
      const float inn = acc[2][r][c2] + bih[wbase + 2 * H_N + j];
      const float rg = 1.f / (1.f + expf(-irv));
      const float zg = 1.f / (1.f + expf(-izv));
      const float ng = tanhf(inn + rg * hn);
      ov[c2] = (1.f - zg) * ng;
    }
    float4 o; o.x = ov[0]; o.y = ov[1]; o.z = ov[2]; o.w = ov[3];
    *reinterpret_cast<float4*>(
        &Hall[((size_t)t * K_N + k) * H_N + bj + tx * 4]) = o;
  }
}

// ---------------------------------------------------------------
// K2: sel_x[t,k] = x[t,:] . W_sel[k, H:] + b_sel[k]
// ---------------------------------------------------------------
__global__ __launch_bounds__(256) void k_selx(
    const float* __restrict__ x, const float* __restrict__ Wsel,
    const float* __restrict__ bsel, float* __restrict__ selx)
{
  const int t = blockIdx.x;
  const int tid = threadIdx.x;
  float p[3] = {0.f, 0.f, 0.f};
  const float4* xr = reinterpret_cast<const float4*>(&x[(size_t)t * I_N]);
  const float4* w[3];
  #pragma unroll
  for (int k = 0; k < 3; ++k)
    w[k] = reinterpret_cast<const float4*>(&Wsel[(size_t)k * (H_N + I_N) + H_N]);
  for (int i = tid; i < I_N / 4; i += 256) {
    const float4 xv = xr[i];
    #pragma unroll
    for (int k = 0; k < 3; ++k) {
      const float4 wv = w[k][i];
      p[k] += xv.x * wv.x + xv.y * wv.y + xv.z * wv.z + xv.w * wv.w;
    }
  }
  #pragma unroll
  for (int k = 0; k < 3; ++k)
    #pragma unroll
    for (int off = 32; off > 0; off >>= 1)
      p[k] += __shfl_down(p[k], off);
  __shared__ float red[4][3];
  const int wid = tid >> 6, lane = tid & 63;
  if (lane == 0) { red[wid][0] = p[0]; red[wid][1] = p[1]; red[wid][2] = p[2]; }
  __syncthreads();
  if (tid < 3) {
    const float s = red[0][tid] + red[1][tid] + red[2][tid] + red[3][tid];
    selx[t * 3 + tid] = s + bsel[tid];
  }
}

// ---------------------------------------------------------------
// K3: L[t,kp,k] = W_sel[k,:H] . H_all[t,kp,:]
// ---------------------------------------------------------------
__global__ __launch_bounds__(256) void k_logits(
    const float* __restrict__ Hall, const float* __restrict__ Wsel,
    float* __restrict__ L)
{
  const int t = blockIdx.x;
  const int tid = threadIdx.x;
  float p[3][3] = {};
  const float4* hp[3];
  const float4* wp[3];
  #pragma unroll
  for (int a = 0; a < 3; ++a) {
    hp[a] = reinterpret_cast<const float4*>(&Hall[((size_t)t * K_N + a) * H_N]);
    wp[a] = reinterpret_cast<const float4*>(&Wsel[(size_t)a * (H_N + I_N)]);
  }
  for (int i = tid; i < H_N / 4; i += 256) {
    float4 hv[3], wv[3];
    #pragma unroll
    for (int a = 0; a < 3; ++a) { hv[a] = hp[a][i]; wv[a] = wp[a][i]; }
    #pragma unroll
    for (int a = 0; a < 3; ++a)
      #pragma unroll
      for (int b = 0; b < 3; ++b)
        p[a][b] += hv[a].x * wv[b].x + hv[a].y * wv[b].y +
                   hv[a].z * wv[b].z + hv[a].w * wv[b].w;
  }
  #pragma unroll
  for (int a = 0; a < 3; ++a)
    #pragma unroll
    for (int b = 0; b < 3; ++b)
      #pragma unroll
      for (int off = 32; off > 0; off >>= 1)
        p[a][b] += __shfl_down(p[a][b], off);
  __shared__ float red[4][9];
  const int wid = tid >> 6, lane = tid & 63;
  if (lane == 0) {
    #pragma unroll
    for (int a = 0; a < 3; ++a)
      #pragma unroll
      for (int b = 0; b < 3; ++b) red[wid][a * 3 + b] = p[a][b];
  }
  __syncthreads();
  if (tid < 9) {
    L[(size_t)t * 9 + tid] =
        red[0][tid] + red[1][tid] + red[2][tid] + red[3][tid];
  }
}

// ---------------------------------------------------------------
// K4+K5: next[] functions + Kogge-Stone scan over {0,1,2}->{0,1,2}
// function composition. One block of 1024 threads, 4 t's per thread.
// ---------------------------------------------------------------
#define FID 0x00020100u

__device__ __forceinline__ uint32_t fcompose(uint32_t after, uint32_t first) {
  uint32_t r = 0;
  #pragma unroll
  for (int xv = 0; xv < 3; ++xv) {
    const uint32_t g = (first >> (8 * xv)) & 3u;
    const uint32_t a = (after >> (8 * g)) & 3u;
    r |= a << (8 * xv);
  }
  return r;
}

__global__ __launch_bounds__(1024) void k_scan(
    const float* __restrict__ L, const float* __restrict__ selx,
    int* __restrict__ kk)
{
  __shared__ uint32_t fn[1024];
  const int tid = threadIdx.x;
  uint32_t f[4];
  #pragma unroll
  for (int r = 0; r < 4; ++r) {
    const int t = tid * 4 + r;
    if (t == 0) { f[r] = FID; continue; }
    const float s0 = selx[t * 3 + 0];
    const float s1 = selx[t * 3 + 1];
    const float s2 = selx[t * 3 + 2];
    uint32_t packed = 0;
    #pragma unroll
    for (int kp = 0; kp < 3; ++kp) {
      const float l0 = L[(size_t)(t - 1) * 9 + kp * 3 + 0] + s0;
      const float l1 = L[(size_t)(t - 1) * 9 + kp * 3 + 1] + s1;
      const float l2 = L[(size_t)(t - 1) * 9 + kp * 3 + 2] + s2;
      uint32_t best = 0; float bv = l0;
      if (l1 > bv) { best = 1; bv = l1; }   // strict > == argmax first-max
      if (l2 > bv) { best = 2; }
      packed |= best << (8 * kp);
    }
    f[r] = packed;
  }
  uint32_t P = fcompose(f[1], f[0]);
  P = fcompose(f[2], P);
  P = fcompose(f[3], P);
  fn[tid] = P;
  __syncthreads();
  for (int s = 1; s < 1024; s <<= 1) {
    const uint32_t cur = fn[tid];
    const uint32_t prev = (tid >= s) ? fn[tid - s] : FID;
    __syncthreads();
    fn[tid] = (tid >= s) ? fcompose(cur, prev) : cur;
    __syncthreads();
  }
  const uint32_t E = (tid == 0) ? FID : fn[tid - 1];
  int c = (int)(E & 3u);
  #pragma unroll
  for (int r = 0; r < 4; ++r) {
    c = (int)((f[r] >> (8 * c)) & 3u);
    kk[tid * 4 + r] = c;
  }
}

// ---------------------------------------------------------------
// K6: gather outputs[t] = H_all[t, kk[t]]; h_last = outputs[T-1]
// ---------------------------------------------------------------
__global__ __launch_bounds__(256) void k_gather(
    const float* __restrict__ Hall, const int* __restrict__ kk,
    float* __restrict__ out)
{
  const int t = blockIdx.x;
  const int sel = kk[t];
  const float4* src = reinterpret_cast<const float4*>(
      &Hall[((size_t)t * K_N + sel) * H_N]);
  float4* dst = reinterpret_cast<float4*>(&out[(size_t)t * H_N]);
  for (int i = threadIdx.x; i < H_N / 4; i += 256) {
    const float4 v = src[i];
    dst[i] = v;
    if (t == T_N - 1)
      reinterpret_cast<float4*>(&out[(size_t)T_N * H_N])[i] = v;
  }
}

// ---------------------------------------------------------------
extern "C" void kernel_launch(void* const* d_in, const int* in_sizes, int n_in,
                              void* d_out, int out_size, void* d_ws, size_t ws_size,
                              hipStream_t stream)
{
  const float* x    = (const float*)d_in[0];
  const float* Wih  = (const float*)d_in[1];
  // d_in[2] = W_hh: unused by the reference computation
  const float* bih  = (const float*)d_in[3];
  const float* bhh  = (const float*)d_in[4];
  const float* Wsel = (const float*)d_in[5];
  const float* bsel = (const float*)d_in[6];
  float* out = (float*)d_out;

  float* Hall = (float*)d_ws;                                   // T*K*H f32
  float* selx = Hall + (size_t)T_N * K_N * H_N;                 // T*K
  float* L    = selx + (size_t)T_N * K_N;                       // T*9
  int*   kk   = (int*)(L + (size_t)T_N * 9);                    // T

  k_gates <<<dim3(T_N / TM, H_N / TN, K_N), 256, 0, stream>>>(x, Wih, bih, bhh, Hall);
  k_selx  <<<dim3(T_N), 256, 0, stream>>>(x, Wsel, bsel, selx);
  k_logits<<<dim3(T_N), 256, 0, stream>>>(Hall, Wsel, L);
  k_scan  <<<dim3(1), 1024, 0, stream>>>(L, selx, kk);
  k_gather<<<dim3(T_N), 256, 0, stream>>>(Hall, kk, out);
}